// Round 7
// baseline (320.658 us; speedup 1.0000x reference)
//
#include <hip/hip_runtime.h>
#include <hip/hip_fp16.h>
#include <hip/hip_cooperative_groups.h>

namespace cg = cooperative_groups;

#define N 256
#define D 2048
#define MARGIN_F 0.3f
#define EPS_F 1e-12f
#define SQRT_EPS_F 1e-6f
#define KSLICES 16           // K-chunks of 128 (mega path)

typedef float v4f __attribute__((ext_vector_type(4)));
typedef short bf16x8 __attribute__((ext_vector_type(8)));

static __device__ __forceinline__ unsigned short f2bf_rne(float f) {
    union { float f; unsigned u; } v; v.f = f;
    unsigned r = v.u + 0x7fffu + ((v.u >> 16) & 1u);
    return (unsigned short)(r >> 16);
}

// ---- mega kernel: conv_sq -> grid.sync -> gram(MFMA) -> grid.sync -> fused -
// grid 1024 x 256 (exactly 4 blocks/CU; launch_bounds(256,4) caps VGPR at 128
// so cooperative co-residency is guaranteed).
__global__ __launch_bounds__(256, 4) void mega_kernel(const float* __restrict__ x,
                                                      const int* __restrict__ targets,
                                                      unsigned short* __restrict__ xb,
                                                      float* __restrict__ sq,
                                                      float* __restrict__ part,
                                                      float* __restrict__ out) {
    cg::grid_group grid = cg::this_grid();
    __shared__ __align__(16) float drow[N];
    __shared__ int lab[N];
    __shared__ float red[4];
    const int b = blockIdx.x;
    const int tid = threadIdx.x;

    // ---- stage 1: xb = bf16(x), sq[row] = sum x^2 (blocks 0..255) ----
    if (b < 256) {
        const float* xr = x + (size_t)b * D + tid * 8;
        float4 v0 = *(const float4*)(xr);
        float4 v1 = *(const float4*)(xr + 4);
        float acc = v0.x * v0.x + v0.y * v0.y + v0.z * v0.z + v0.w * v0.w +
                    v1.x * v1.x + v1.y * v1.y + v1.z * v1.z + v1.w * v1.w;
        union { unsigned short h[8]; uint4 u; } pk;
        pk.h[0] = f2bf_rne(v0.x); pk.h[1] = f2bf_rne(v0.y);
        pk.h[2] = f2bf_rne(v0.z); pk.h[3] = f2bf_rne(v0.w);
        pk.h[4] = f2bf_rne(v1.x); pk.h[5] = f2bf_rne(v1.y);
        pk.h[6] = f2bf_rne(v1.z); pk.h[7] = f2bf_rne(v1.w);
        *(uint4*)(xb + (size_t)b * D + tid * 8) = pk.u;
#pragma unroll
        for (int off = 32; off > 0; off >>= 1) acc += __shfl_down(acc, off, 64);
        if ((tid & 63) == 0) red[tid >> 6] = acc;
        __syncthreads();
        if (tid == 0) sq[b] = red[0] + red[1] + red[2] + red[3];
    }
    grid.sync();

    // ---- stage 2: Gram partials via MFMA, all 1024 blocks ----
    // block b -> (bi = b&7, bj = (b>>3)&7, ks = b>>6), K-chunk 128.
    // part layout: part[i*(KSLICES*N) + ks*N + j], fp32.
    {
        const int w = tid >> 6;
        const int l = tid & 63;
        const int i0 = (b & 7) * 32 + (w >> 1) * 16;
        const int j0 = ((b >> 3) & 7) * 32 + (w & 1) * 16;
        const int ks = b >> 6;
        const int kq = (l >> 4) * 8;
        const unsigned short* pa = xb + (size_t)(i0 + (l & 15)) * D + ks * 128 + kq;
        const unsigned short* pb = xb + (size_t)(j0 + (l & 15)) * D + ks * 128 + kq;
        v4f acc = {0.f, 0.f, 0.f, 0.f};
#pragma unroll
        for (int t = 0; t < 4; ++t) {
            bf16x8 af = *(const bf16x8*)(pa + t * 32);
            bf16x8 bf = *(const bf16x8*)(pb + t * 32);
            acc = __builtin_amdgcn_mfma_f32_16x16x32_bf16(af, bf, acc, 0, 0, 0);
        }
        // C/D: row = (l>>4)*4 + r, col = l&15
        float* pp = part + ((size_t)(i0 + (l >> 4) * 4) * KSLICES + ks) * N + j0 + (l & 15);
#pragma unroll
        for (int r = 0; r < 4; ++r)
            pp[(size_t)r * KSLICES * N] = acc[r];
    }
    grid.sync();

    // ---- stage 3: fused reduce + dist + triplet store ----
    // block b -> (a = b&255, quarter qy = b>>8).
    {
        const int a = b & 255;
        const int qy = b >> 8;
        lab[tid] = targets[tid];

        const float* pr = part + (size_t)a * (KSLICES * N);
        float dot = 0.f;
#pragma unroll
        for (int ks = 0; ks < KSLICES; ++ks)
            dot += pr[ks * N + tid];
        drow[tid] = (tid == a) ? SQRT_EPS_F
                               : sqrtf(fmaxf(sq[a] + sq[tid] - 2.f * dot, EPS_F));
        __syncthreads();

        const int la = lab[a];
        const int lane = tid & 63;
        const int pq = tid >> 6;
        const int p0 = qy * 64 + pq * 16;

        v4f dan = *(const v4f*)(drow + lane * 4);
        v4f mb = MARGIN_F - dan;
        v4f nokv = {(lab[lane * 4 + 0] != la) ? 1.f : 0.f,
                    (lab[lane * 4 + 1] != la) ? 1.f : 0.f,
                    (lab[lane * 4 + 2] != la) ? 1.f : 0.f,
                    (lab[lane * 4 + 3] != la) ? 1.f : 0.f};

        float* obase = out + ((size_t)a << 16) + lane * 4;
#pragma unroll 4
        for (int i = 0; i < 16; ++i) {
            int p = p0 + i;                   // wave-uniform
            v4f r = {0.f, 0.f, 0.f, 0.f};
            if (lab[p] == la) {               // wave-uniform branch
                float dap = drow[p];
                v4f t = dap + mb;
                t.x = fmaxf(t.x, EPS_F);
                t.y = fmaxf(t.y, EPS_F);
                t.z = fmaxf(t.z, EPS_F);
                t.w = fmaxf(t.w, EPS_F);
                r = t * nokv;
            }
            *(v4f*)(obase + (size_t)p * N) = r;
        }
    }
}

// ---------------- fallback path (tiny ws): VALU pipeline --------------------
__global__ __launch_bounds__(64) void sq_kernel(const float* __restrict__ x,
                                                float* __restrict__ sq) {
    int row = blockIdx.x;
    int lane = threadIdx.x;
    const float4* xr = (const float4*)(x + (size_t)row * D);
    float acc = 0.f;
#pragma unroll
    for (int it = 0; it < 8; ++it) {
        float4 v = xr[lane + 64 * it];
        acc += v.x * v.x + v.y * v.y + v.z * v.z + v.w * v.w;
    }
#pragma unroll
    for (int off = 32; off > 0; off >>= 1) acc += __shfl_down(acc, off, 64);
    if (lane == 0) sq[row] = acc;
}

__global__ __launch_bounds__(256) void gram_valu_kernel(const float* __restrict__ x,
                                                        __half* __restrict__ part) {
    __shared__ __align__(16) float As[64 * 68];
    __shared__ __align__(16) float Bs[64 * 68];
    const int i0 = blockIdx.x * 64, j0 = blockIdx.y * 64, k0 = blockIdx.z * 64;
    const int tid = threadIdx.x;
#pragma unroll
    for (int it = 0; it < 4; ++it) {
        int f = tid + 256 * it;
        int row = f >> 4;
        int c4 = f & 15;
        int sc4 = c4 ^ ((row >> 2) & 15);
        float4 va = *(const float4*)(x + (size_t)(i0 + row) * D + k0 + c4 * 4);
        float4 vb = *(const float4*)(x + (size_t)(j0 + row) * D + k0 + c4 * 4);
        *(float4*)(As + row * 68 + sc4 * 4) = va;
        *(float4*)(Bs + row * 68 + sc4 * 4) = vb;
    }
    __syncthreads();
    const int tx = tid & 15, ty = tid >> 4;
    float acc[4][4];
#pragma unroll
    for (int r = 0; r < 4; ++r)
#pragma unroll
        for (int c = 0; c < 4; ++c) acc[r][c] = 0.f;
#pragma unroll
    for (int k4 = 0; k4 < 16; ++k4) {
        float4 a[4], b[4];
        const int ca = (k4 ^ ty) << 2, cb = (k4 ^ tx) << 2;
#pragma unroll
        for (int r = 0; r < 4; ++r) {
            a[r] = *(const float4*)(As + (ty * 4 + r) * 68 + ca);
            b[r] = *(const float4*)(Bs + (tx * 4 + r) * 68 + cb);
        }
#pragma unroll
        for (int r = 0; r < 4; ++r)
#pragma unroll
            for (int c = 0; c < 4; ++c)
                acc[r][c] += a[r].x * b[c].x + a[r].y * b[c].y +
                             a[r].z * b[c].z + a[r].w * b[c].w;
    }
    __half* pout = part + (size_t)blockIdx.z * (N * N);
#pragma unroll
    for (int r = 0; r < 4; ++r) {
        int gi = i0 + ty * 4 + r;
        union { __half2 h2[2]; uint2 u; } pk;
        pk.h2[0] = __floats2half2_rn(acc[r][0], acc[r][1]);
        pk.h2[1] = __floats2half2_rn(acc[r][2], acc[r][3]);
        *(uint2*)(pout + (size_t)gi * N + j0 + tx * 4) = pk.u;
    }
}

__global__ __launch_bounds__(256) void dist_kernel(const __half* __restrict__ part,
                                                   const float* __restrict__ sq,
                                                   float* __restrict__ dist) {
    const int a = blockIdx.x;
    const int tid = threadIdx.x;
    float dot = 0.f;
    const __half* base = part + a * N + tid;
#pragma unroll 8
    for (int ks = 0; ks < 32; ++ks)
        dot += __half2float(base[(size_t)ks * (N * N)]);
    dist[a * N + tid] = (tid == a) ? SQRT_EPS_F
                                   : sqrtf(fmaxf(sq[a] + sq[tid] - 2.f * dot, EPS_F));
}

__global__ __launch_bounds__(256) void triplet_kernel(const float* __restrict__ dist,
                                                      const int* __restrict__ targets,
                                                      float* __restrict__ out) {
    __shared__ __align__(16) float drow[N];
    __shared__ int lab[N];
    const int a = blockIdx.x;
    const int p0 = blockIdx.y * 16;
    const int tid = threadIdx.x;
    lab[tid] = targets[tid];
    drow[tid] = dist[a * N + tid];
    __syncthreads();
    const int la = lab[a];
    const int lane = tid & 63;
    const int pq = tid >> 6;
    v4f dan = *(const v4f*)(drow + lane * 4);
    v4f mb = MARGIN_F - dan;
    v4f nokv = {(lab[lane * 4 + 0] != la) ? 1.f : 0.f,
                (lab[lane * 4 + 1] != la) ? 1.f : 0.f,
                (lab[lane * 4 + 2] != la) ? 1.f : 0.f,
                (lab[lane * 4 + 3] != la) ? 1.f : 0.f};
    float* obase = out + ((size_t)a << 16) + lane * 4;
#pragma unroll
    for (int j = 0; j < 4; ++j) {
        int p = p0 + pq * 4 + j;
        v4f r = {0.f, 0.f, 0.f, 0.f};
        if (lab[p] == la) {
            float dap = drow[p];
            v4f t = dap + mb;
            t.x = fmaxf(t.x, EPS_F);
            t.y = fmaxf(t.y, EPS_F);
            t.z = fmaxf(t.z, EPS_F);
            t.w = fmaxf(t.w, EPS_F);
            r = t * nokv;
        }
        *(v4f*)(obase + (size_t)p * N) = r;
    }
}

extern "C" void kernel_launch(void* const* d_in, const int* in_sizes, int n_in,
                              void* d_out, int out_size, void* d_ws, size_t ws_size,
                              hipStream_t stream) {
    const float* x = (const float*)d_in[0];
    const int* targets = (const int*)d_in[1];
    float* out = (float*)d_out;
    float* ws = (float*)d_ws;

    // ws layout (mega path): sq[256] | xb[256*2048 bf16 = 1MB] | part[16*256*256 fp32 = 4MB]
    float* sq = ws;
    unsigned short* xb = (unsigned short*)(ws + 256);
    float* part = (float*)(xb + (size_t)N * D);
    size_t need = 256 * 4 + (size_t)N * D * 2 + (size_t)KSLICES * N * N * 4 + 1024;

    if (ws_size >= need) {
        void* args[] = {(void*)&x, (void*)&targets, (void*)&xb,
                        (void*)&sq, (void*)&part, (void*)&out};
        hipLaunchCooperativeKernel((const void*)mega_kernel, dim3(1024), dim3(256),
                                   args, 0, stream);
    } else {
        // Borrow d_out (4 MB of 64 MB) for fp16 partials; dist lives in ws.
        __half* hpart = (__half*)d_out;
        float* sq2 = ws;
        float* dist = ws + 256;
        sq_kernel<<<256, 64, 0, stream>>>(x, sq2);
        gram_valu_kernel<<<dim3(4, 4, 32), 256, 0, stream>>>(x, hpart);
        dist_kernel<<<256, 256, 0, stream>>>(hpart, sq2, dist);
        triplet_kernel<<<dim3(256, 16), 256, 0, stream>>>(dist, targets, out);
    }
}

// Round 8
// 85.009 us; speedup vs baseline: 3.7720x; 3.7720x over previous
//
#include <hip/hip_runtime.h>
#include <hip/hip_fp16.h>

#define N 256
#define D 2048
#define MARGIN_F 0.3f
#define EPS_F 1e-12f
#define SQRT_EPS_F 1e-6f
#define KSLICES 8            // K-chunks of 256

typedef float v4f __attribute__((ext_vector_type(4)));
typedef short bf16x8 __attribute__((ext_vector_type(8)));

static __device__ __forceinline__ unsigned short f2bf_rne(float f) {
    union { float f; unsigned u; } v; v.f = f;
    unsigned r = v.u + 0x7fffu + ((v.u >> 16) & 1u);
    return (unsigned short)(r >> 16);
}

// ---- kernel 0: xb = bf16(x) (RNE) and sq[i] = sum_k x[i][k]^2 (fp32) -------
__global__ __launch_bounds__(256) void conv_sq_kernel(const float* __restrict__ x,
                                                      unsigned short* __restrict__ xb,
                                                      float* __restrict__ sq) {
    __shared__ float red[4];
    const int row = blockIdx.x;
    const int tid = threadIdx.x;
    const float* xr = x + (size_t)row * D + tid * 8;
    float4 v0 = *(const float4*)(xr);
    float4 v1 = *(const float4*)(xr + 4);
    float acc = v0.x * v0.x + v0.y * v0.y + v0.z * v0.z + v0.w * v0.w +
                v1.x * v1.x + v1.y * v1.y + v1.z * v1.z + v1.w * v1.w;
    union { unsigned short h[8]; uint4 u; } pk;
    pk.h[0] = f2bf_rne(v0.x); pk.h[1] = f2bf_rne(v0.y);
    pk.h[2] = f2bf_rne(v0.z); pk.h[3] = f2bf_rne(v0.w);
    pk.h[4] = f2bf_rne(v1.x); pk.h[5] = f2bf_rne(v1.y);
    pk.h[6] = f2bf_rne(v1.z); pk.h[7] = f2bf_rne(v1.w);
    *(uint4*)(xb + (size_t)row * D + tid * 8) = pk.u;
#pragma unroll
    for (int off = 32; off > 0; off >>= 1) acc += __shfl_down(acc, off, 64);
    if ((tid & 63) == 0) red[tid >> 6] = acc;
    __syncthreads();
    if (tid == 0) sq[row] = red[0] + red[1] + red[2] + red[3];
}

// ---- kernel 1: Gram partials via MFMA, fragments direct from L2 ------------
// grid (8,8,8): block = 32x32 tile (4 waves of 16x16), K-chunk 256.
// No LDS. part layout: part[i*(KSLICES*N) + ks*N + j], fp32.
// Gram is symmetric, so any consistent lane->k permutation in A/B cancels.
__global__ __launch_bounds__(256) void gram_mfma_kernel(const unsigned short* __restrict__ xb,
                                                        float* __restrict__ part) {
    const int w = threadIdx.x >> 6;
    const int l = threadIdx.x & 63;
    const int i0 = blockIdx.x * 32 + (w >> 1) * 16;
    const int j0 = blockIdx.y * 32 + (w & 1) * 16;
    const int ks = blockIdx.z;
    const int kq = (l >> 4) * 8;
    const unsigned short* pa = xb + (size_t)(i0 + (l & 15)) * D + ks * 256 + kq;
    const unsigned short* pb = xb + (size_t)(j0 + (l & 15)) * D + ks * 256 + kq;
    v4f acc = {0.f, 0.f, 0.f, 0.f};
#pragma unroll
    for (int t = 0; t < 8; ++t) {
        bf16x8 af = *(const bf16x8*)(pa + t * 32);
        bf16x8 bf = *(const bf16x8*)(pb + t * 32);
        acc = __builtin_amdgcn_mfma_f32_16x16x32_bf16(af, bf, acc, 0, 0, 0);
    }
    // C/D: row = (l>>4)*4 + r, col = l&15
    float* pp = part + ((size_t)(i0 + (l >> 4) * 4) * KSLICES + ks) * N + j0 + (l & 15);
#pragma unroll
    for (int r = 0; r < 4; ++r)
        pp[(size_t)r * KSLICES * N] = acc[r];
}

// ---- kernel 2: fused reduce + dist + triplet -------------------------------
// grid (256, 2). Phase 1: sum 8 contiguous fp32 slices -> dist row in LDS
// (diag forced to sqrt(eps), replicating the reference's clip branch).
// Phase 2: stream the 128KB output strip with plain float4 stores.
__global__ __launch_bounds__(256) void fused_kernel(const float* __restrict__ part,
                                                    const float* __restrict__ sq,
                                                    const int* __restrict__ targets,
                                                    float* __restrict__ out) {
    __shared__ __align__(16) float drow[N];
    __shared__ int lab[N];
    const int a = blockIdx.x;
    const int tid = threadIdx.x;
    lab[tid] = targets[tid];

    const float* pr = part + (size_t)a * (KSLICES * N);
    float dot = 0.f;
#pragma unroll
    for (int ks = 0; ks < KSLICES; ++ks)
        dot += pr[ks * N + tid];
    drow[tid] = (tid == a) ? SQRT_EPS_F
                           : sqrtf(fmaxf(sq[a] + sq[tid] - 2.f * dot, EPS_F));
    __syncthreads();

    const int la = lab[a];
    const int lane = tid & 63;
    const int pq = tid >> 6;
    const int p0 = blockIdx.y * 128 + pq * 32;

    v4f dan = *(const v4f*)(drow + lane * 4);
    v4f mb = MARGIN_F - dan;
    v4f nokv = {(lab[lane * 4 + 0] != la) ? 1.f : 0.f,
                (lab[lane * 4 + 1] != la) ? 1.f : 0.f,
                (lab[lane * 4 + 2] != la) ? 1.f : 0.f,
                (lab[lane * 4 + 3] != la) ? 1.f : 0.f};

    float* obase = out + ((size_t)a << 16) + lane * 4;
#pragma unroll 4
    for (int i = 0; i < 32; ++i) {
        int p = p0 + i;                   // wave-uniform
        v4f r = {0.f, 0.f, 0.f, 0.f};
        if (lab[p] == la) {               // wave-uniform branch
            float dap = drow[p];
            v4f t = dap + mb;
            t.x = fmaxf(t.x, EPS_F);
            t.y = fmaxf(t.y, EPS_F);
            t.z = fmaxf(t.z, EPS_F);
            t.w = fmaxf(t.w, EPS_F);
            r = t * nokv;
        }
        *(v4f*)(obase + (size_t)p * N) = r;
    }
}

// ---------------- fallback path (tiny ws): VALU pipeline --------------------
__global__ __launch_bounds__(64) void sq_kernel(const float* __restrict__ x,
                                                float* __restrict__ sq) {
    int row = blockIdx.x;
    int lane = threadIdx.x;
    const float4* xr = (const float4*)(x + (size_t)row * D);
    float acc = 0.f;
#pragma unroll
    for (int it = 0; it < 8; ++it) {
        float4 v = xr[lane + 64 * it];
        acc += v.x * v.x + v.y * v.y + v.z * v.z + v.w * v.w;
    }
#pragma unroll
    for (int off = 32; off > 0; off >>= 1) acc += __shfl_down(acc, off, 64);
    if (lane == 0) sq[row] = acc;
}

__global__ __launch_bounds__(256) void gram_valu_kernel(const float* __restrict__ x,
                                                        __half* __restrict__ part) {
    __shared__ __align__(16) float As[64 * 68];
    __shared__ __align__(16) float Bs[64 * 68];
    const int i0 = blockIdx.x * 64, j0 = blockIdx.y * 64, k0 = blockIdx.z * 64;
    const int tid = threadIdx.x;
#pragma unroll
    for (int it = 0; it < 4; ++it) {
        int f = tid + 256 * it;
        int row = f >> 4;
        int c4 = f & 15;
        int sc4 = c4 ^ ((row >> 2) & 15);
        float4 va = *(const float4*)(x + (size_t)(i0 + row) * D + k0 + c4 * 4);
        float4 vb = *(const float4*)(x + (size_t)(j0 + row) * D + k0 + c4 * 4);
        *(float4*)(As + row * 68 + sc4 * 4) = va;
        *(float4*)(Bs + row * 68 + sc4 * 4) = vb;
    }
    __syncthreads();
    const int tx = tid & 15, ty = tid >> 4;
    float acc[4][4];
#pragma unroll
    for (int r = 0; r < 4; ++r)
#pragma unroll
        for (int c = 0; c < 4; ++c) acc[r][c] = 0.f;
#pragma unroll
    for (int k4 = 0; k4 < 16; ++k4) {
        float4 a[4], b[4];
        const int ca = (k4 ^ ty) << 2, cb = (k4 ^ tx) << 2;
#pragma unroll
        for (int r = 0; r < 4; ++r) {
            a[r] = *(const float4*)(As + (ty * 4 + r) * 68 + ca);
            b[r] = *(const float4*)(Bs + (tx * 4 + r) * 68 + cb);
        }
#pragma unroll
        for (int r = 0; r < 4; ++r)
#pragma unroll
            for (int c = 0; c < 4; ++c)
                acc[r][c] += a[r].x * b[c].x + a[r].y * b[c].y +
                             a[r].z * b[c].z + a[r].w * b[c].w;
    }
    __half* pout = part + (size_t)blockIdx.z * (N * N);
#pragma unroll
    for (int r = 0; r < 4; ++r) {
        int gi = i0 + ty * 4 + r;
        union { __half2 h2[2]; uint2 u; } pk;
        pk.h2[0] = __floats2half2_rn(acc[r][0], acc[r][1]);
        pk.h2[1] = __floats2half2_rn(acc[r][2], acc[r][3]);
        *(uint2*)(pout + (size_t)gi * N + j0 + tx * 4) = pk.u;
    }
}

__global__ __launch_bounds__(256) void dist_kernel(const __half* __restrict__ part,
                                                   const float* __restrict__ sq,
                                                   float* __restrict__ dist) {
    const int a = blockIdx.x;
    const int tid = threadIdx.x;
    float dot = 0.f;
    const __half* base = part + a * N + tid;
#pragma unroll 8
    for (int ks = 0; ks < 32; ++ks)
        dot += __half2float(base[(size_t)ks * (N * N)]);
    dist[a * N + tid] = (tid == a) ? SQRT_EPS_F
                                   : sqrtf(fmaxf(sq[a] + sq[tid] - 2.f * dot, EPS_F));
}

__global__ __launch_bounds__(256) void triplet_kernel(const float* __restrict__ dist,
                                                      const int* __restrict__ targets,
                                                      float* __restrict__ out) {
    __shared__ __align__(16) float drow[N];
    __shared__ int lab[N];
    const int a = blockIdx.x;
    const int p0 = blockIdx.y * 16;
    const int tid = threadIdx.x;
    lab[tid] = targets[tid];
    drow[tid] = dist[a * N + tid];
    __syncthreads();
    const int la = lab[a];
    const int lane = tid & 63;
    const int pq = tid >> 6;
    v4f dan = *(const v4f*)(drow + lane * 4);
    v4f mb = MARGIN_F - dan;
    v4f nokv = {(lab[lane * 4 + 0] != la) ? 1.f : 0.f,
                (lab[lane * 4 + 1] != la) ? 1.f : 0.f,
                (lab[lane * 4 + 2] != la) ? 1.f : 0.f,
                (lab[lane * 4 + 3] != la) ? 1.f : 0.f};
    float* obase = out + ((size_t)a << 16) + lane * 4;
#pragma unroll
    for (int j = 0; j < 4; ++j) {
        int p = p0 + pq * 4 + j;
        v4f r = {0.f, 0.f, 0.f, 0.f};
        if (lab[p] == la) {
            float dap = drow[p];
            v4f t = dap + mb;
            t.x = fmaxf(t.x, EPS_F);
            t.y = fmaxf(t.y, EPS_F);
            t.z = fmaxf(t.z, EPS_F);
            t.w = fmaxf(t.w, EPS_F);
            r = t * nokv;
        }
        *(v4f*)(obase + (size_t)p * N) = r;
    }
}

extern "C" void kernel_launch(void* const* d_in, const int* in_sizes, int n_in,
                              void* d_out, int out_size, void* d_ws, size_t ws_size,
                              hipStream_t stream) {
    const float* x = (const float*)d_in[0];
    const int* targets = (const int*)d_in[1];
    float* out = (float*)d_out;
    float* ws = (float*)d_ws;

    // ws layout (full path): sq[256] | xb[256*2048 bf16 = 1MB] | part[8*256*256 fp32 = 2MB]
    float* sq = ws;
    unsigned short* xb = (unsigned short*)(ws + 256);
    float* part = (float*)(xb + (size_t)N * D);
    size_t need = 256 * 4 + (size_t)N * D * 2 + (size_t)KSLICES * N * N * 4 + 1024;

    if (ws_size >= need) {
        conv_sq_kernel<<<256, 256, 0, stream>>>(x, xb, sq);
        gram_mfma_kernel<<<dim3(8, 8, KSLICES), 256, 0, stream>>>(xb, part);
        fused_kernel<<<dim3(256, 2), 256, 0, stream>>>(part, sq, targets, out);
    } else {
        // Borrow d_out (4 MB of 64 MB) for fp16 partials; dist lives in ws.
        __half* hpart = (__half*)d_out;
        float* sq2 = ws;
        float* dist = ws + 256;
        sq_kernel<<<256, 64, 0, stream>>>(x, sq2);
        gram_valu_kernel<<<dim3(4, 4, 32), 256, 0, stream>>>(x, hpart);
        dist_kernel<<<256, 256, 0, stream>>>(hpart, sq2, dist);
        triplet_kernel<<<dim3(256, 16), 256, 0, stream>>>(dist, targets, out);
    }
}